// Round 15
// baseline (665.469 us; speedup 1.0000x reference)
//
#include <hip/hip_runtime.h>
#include <stdint.h>

typedef short bf16x8 __attribute__((ext_vector_type(8)));
typedef float f32x16 __attribute__((ext_vector_type(16)));

#define BM 256
#define BN 256
#define BK 64
#define ABUF_U 16384   // 256*64 ushorts (32KB) A region
#define BUF_U  32768   // A+B per buffer in ushorts (64KB); 2 buffers = 128KB

#define AS1 __attribute__((address_space(1)))
#define AS3 __attribute__((address_space(3)))

__device__ __forceinline__ ushort f2bf(float x) {
    uint32_t u = __float_as_uint(x);
    u += 0x7FFFu + ((u >> 16) & 1u);
    return (ushort)(u >> 16);
}
__device__ __forceinline__ float bf2f(ushort u) {
    return __uint_as_float((uint)u << 16);
}

__device__ __forceinline__ void gload16(const void* g, void* l) {
    __builtin_amdgcn_global_load_lds((const AS1 void*)g, (AS3 void*)l, 16, 0, 0);
}

// issue 2 staging loads (i0=0 -> A pair, i0=2 -> B pair) for K-offset kt
#define ISSUE2(kt, buf, i0)                                                          \
    do {                                                                             \
        gload16(((i0) < 2 ? Ap : Bp) + goff[i0] + (kt), smem + (buf)*BUF_U + loff[i0]); \
        gload16(((i0) < 2 ? Ap : Bp) + goff[(i0)+1] + (kt), smem + (buf)*BUF_U + loff[(i0)+1]); \
    } while (0)

// C[M,N] = A[M,K] * B[N,K]^T, bf16 MFMA 32x32x16.  (r12 schedule, 1024 threads)
// 256x256 tile, 1024 threads (16 waves: 4M x 4N, per-wave 64x64 = 2x2 32x32
// tiles). 16 waves = 4 waves/SIMD (vs 2 at 512 threads): one wave's vmcnt /
// ds_read stall overlaps another's MFMA on the same SIMD (m114, intra-block).
// K-loop: 2 barriers/tile; interior (12 ds_read_b128 + 16 MFMA + 2 prefetch
// gloads per wave) left to compiler lgkmcnt pipelining. Counted vmcnt(2)/tile
// (A-pair at entry, B-pair at kk=0 -> 4-deep queue, waits exactly prev tile).
// 32x32 C/D layout -> full-line coalesced row-major stores. XCD swizzle (m204).
// Transposed stores: lanes lr/lr+32 merged via shfl_xor(32) into 16B stores.
// Dual pointer sets: blocks with z >= zsplit use the *2 pointers, zl = z-zsplit.
// MODE 0: bf16 out = acc (+bias), optional transposed copy (per-batch [col][row])
// MODE 1: scores: e=exp(tanh(acc)); write E + E^T bf16; atomic rowsum/colsum
// MODE 2: bf16 out = acc / scale[row]
// MODE 3: bf16 out = acc + bias[col] + bf16 resid[row,col]   (pre-LN tensor)
template<int MODE, bool HAS_BIAS, bool WRITE_T>
__global__ __launch_bounds__(1024)
void gemm_bt(const ushort* __restrict__ Aptr_, const ushort* __restrict__ Bptr_,
             void* __restrict__ Cptr_, ushort* __restrict__ CTptr_,
             const float* __restrict__ bias, const ushort* __restrict__ resid_,
             float* __restrict__ rsum_, float* __restrict__ csum_,
             const float* __restrict__ scale_,
             const ushort* __restrict__ Aptr2_, const ushort* __restrict__ Bptr2_,
             void* __restrict__ Cptr2_, const float* __restrict__ scale2_, int zsplit,
             int M, int N, int K, int lda, int ldb, int ldc,
             long sA, long sB, long sC, long sCT, long sSum,
             int ldct, int rbshift)
{
    extern __shared__ ushort smem[];   // 2 * BUF_U ushorts (128KB)

    // ---- bijective XCD swizzle (T1, m204) ----
    const int gx = gridDim.x, gy = gridDim.y;
    const int nwg = gx * gy * (int)gridDim.z;
    int flat = ((int)blockIdx.z * gy + (int)blockIdx.y) * gx + (int)blockIdx.x;
    {
        const int q8 = nwg >> 3, r8 = nwg & 7;
        const int xcd = flat & 7, loc = flat >> 3;
        flat = (xcd < r8 ? xcd * (q8 + 1) : r8 * (q8 + 1) + (xcd - r8) * q8) + loc;
    }
    const int z   = flat / (gx * gy);
    const int rem = flat - z * (gx * gy);
    const int m0  = (rem % gx) * BM;
    const int n0  = (rem / gx) * BN;

    const bool sec = (z >= zsplit);
    const int  zl  = sec ? z - zsplit : z;

    const int tid  = threadIdx.x;
    const int lane = tid & 63;
    const int wave = tid >> 6;         // 0..15
    const int wr   = wave >> 2;        // 0..3 -> rows wr*64..+64
    const int wcn  = wave & 3;         // 0..3 -> cols wcn*64..+64
    const int lr   = lane & 31, lh = lane >> 5;

    const ushort* Ap = (sec ? Aptr2_ : Aptr_) + (long)zl * sA;
    const ushort* Bp = (sec ? Bptr2_ : Bptr_) + (long)zl * sB;

    // staging: linear LDS dest, XOR-swizzled global source chunk (both-sides).
    long goff[4]; int loff[4];
    #pragma unroll
    for (int u = 0; u < 2; ++u) {
        const int li  = u * 1024 + tid;      // chunk 0..2047 (A and B each)
        const int row = li >> 3;             // 0..255
        const int gck = (li & 7) ^ (row & 7);
        goff[u]     = (long)(m0 + row) * lda + gck * 8;
        loff[u]     = li * 8;
        goff[u + 2] = (long)(n0 + row) * ldb + gck * 8;
        loff[u + 2] = ABUF_U + li * 8;
    }

    f32x16 acc[2][2] = {};

    const int nk = K / BK;
    // prologue: stage tile 0 into buf 0 (4 loads/thread)
    ISSUE2(0, 0, 0); ISSUE2(0, 0, 2);

    for (int t = 0; t < nk; ++t) {
        const int cur = t & 1, nxt = cur ^ 1;
        const ushort* As = smem + cur * BUF_U;
        const ushort* Bs = As + ABUF_U;
        const bool pf = (t + 1 < nk);
        const int kt1 = (t + 1) * BK;

        if (pf) {
            ISSUE2(kt1, nxt, 0);
            asm volatile("s_waitcnt vmcnt(2)" ::: "memory");  // tile t landed; A-pair of t+1 in flight
        } else {
            asm volatile("s_waitcnt vmcnt(0)" ::: "memory");  // tail drain
        }
        __builtin_amdgcn_s_barrier();

        // tile interior: no manual fences — compiler pipelines ds_read vs MFMA
        #pragma unroll
        for (int kk = 0; kk < 4; ++kk) {          // 4 k-steps of 16
            bf16x8 af[2], bfv[2];
            #pragma unroll
            for (int tm = 0; tm < 2; ++tm) {
                const int row = wr * 64 + tm * 32 + lr;
                const int ck  = (kk * 2 + lh) ^ (row & 7);
                af[tm] = *(const bf16x8*)&As[row * BK + ck * 8];
            }
            #pragma unroll
            for (int tn = 0; tn < 2; ++tn) {
                const int row = wcn * 64 + tn * 32 + lr;
                const int ck  = (kk * 2 + lh) ^ (row & 7);
                bfv[tn] = *(const bf16x8*)&Bs[row * BK + ck * 8];
            }
            if (pf && kk == 0) ISSUE2(kt1, nxt, 2);
            #pragma unroll
            for (int tm = 0; tm < 2; ++tm)
                #pragma unroll
                for (int tn = 0; tn < 2; ++tn)
                    acc[tm][tn] = __builtin_amdgcn_mfma_f32_32x32x16_bf16(
                        af[tm], bfv[tn], acc[tm][tn], 0, 0, 0);
        }

        asm volatile("s_waitcnt lgkmcnt(0)" ::: "memory");  // my reads of cur done
        __builtin_amdgcn_s_barrier();                        // all waves done -> cur reusable
    }

    // ---- epilogues (direct stores; 32x32 layout -> full-line coalescing) ----
    const int colb0 = n0 + wcn * 64 + lr;         // tn=0 col
    const int rowbw = m0 + wr * 64 + 4 * lh;      // + tm*32 + q*8 + s

    if constexpr (MODE == 3) {
        ushort* Cp = (ushort*)Cptr_;
        #pragma unroll
        for (int tm = 0; tm < 2; ++tm)
            #pragma unroll
            for (int tn = 0; tn < 2; ++tn) {
                const int col = colb0 + tn * 32;
                const float bv = bias[col];
                #pragma unroll
                for (int q = 0; q < 4; ++q)
                    #pragma unroll
                    for (int s = 0; s < 4; ++s) {
                        const int row = rowbw + tm * 32 + q * 8 + s;
                        const long idx = (long)row * ldc + col;
                        Cp[idx] = f2bf(acc[tm][tn][q * 4 + s] + bv + bf2f(resid_[idx]));
                    }
            }
    } else if constexpr (MODE == 0) {
        ushort* Cp = (ushort*)Cptr_ + zl * sC;
        #pragma unroll
        for (int tm = 0; tm < 2; ++tm) {
            uint pk[2][8];
            #pragma unroll
            for (int tn = 0; tn < 2; ++tn) {
                const int col = colb0 + tn * 32;
                const float bv = HAS_BIAS ? bias[col] : 0.f;
                ushort us[16];
                #pragma unroll
                for (int rr = 0; rr < 16; ++rr) us[rr] = f2bf(acc[tm][tn][rr] + bv);
                #pragma unroll
                for (int q = 0; q < 4; ++q)
                    #pragma unroll
                    for (int s = 0; s < 4; ++s)
                        Cp[(long)(rowbw + tm * 32 + q * 8 + s) * ldc + col] = us[q * 4 + s];
                if constexpr (WRITE_T) {
                    #pragma unroll
                    for (int q = 0; q < 4; ++q) {
                        pk[tn][q * 2 + 0] = (uint)us[q * 4 + 0] | ((uint)us[q * 4 + 1] << 16);
                        pk[tn][q * 2 + 1] = (uint)us[q * 4 + 2] | ((uint)us[q * 4 + 3] << 16);
                    }
                }
            }
            if constexpr (WRITE_T) {
                #pragma unroll
                for (int tn = 0; tn < 2; ++tn)
                    #pragma unroll
                    for (int q = 0; q < 4; ++q) {
                        const uint ox = __shfl_xor(pk[tn][q * 2 + 0], 32);
                        const uint oy = __shfl_xor(pk[tn][q * 2 + 1], 32);
                        if (lh == tn) {
                            const uint4 v = (lh == 0)
                                ? make_uint4(pk[tn][q * 2], pk[tn][q * 2 + 1], ox, oy)
                                : make_uint4(ox, oy, pk[tn][q * 2], pk[tn][q * 2 + 1]);
                            const int grm = m0 + wr * 64 + tm * 32 + q * 8;
                            const int bb  = grm >> rbshift;
                            const int ii  = grm & ((1 << rbshift) - 1);
                            const int col = colb0 + tn * 32;
                            *(uint4*)&CTptr_[(long)bb * sCT + (long)col * ldct + ii] = v;
                        }
                    }
            }
        }
    } else if constexpr (MODE == 1) {
        ushort* Ep  = (ushort*)Cptr_ + zl * sC;
        ushort* ETp = CTptr_ + zl * sCT;
        float* rs = rsum_ + zl * sSum;
        float* cs = csum_ + zl * sSum;
        float colp[2] = {0.f, 0.f};
        #pragma unroll
        for (int tm = 0; tm < 2; ++tm) {
            float rowp[16];
            #pragma unroll
            for (int rr = 0; rr < 16; ++rr) rowp[rr] = 0.f;
            uint pk[2][8];
            #pragma unroll
            for (int tn = 0; tn < 2; ++tn) {
                const int col = colb0 + tn * 32;
                ushort us[16];
                #pragma unroll
                for (int rr = 0; rr < 16; ++rr) {
                    const float x  = acc[tm][tn][rr];
                    const float th = 1.f - 2.f / (__expf(2.f * x) + 1.f);  // tanh(x)
                    const float e  = __expf(th);
                    rowp[rr] += e;
                    colp[tn] += e;
                    us[rr] = f2bf(e);
                }
                #pragma unroll
                for (int q = 0; q < 4; ++q) {
                    #pragma unroll
                    for (int s = 0; s < 4; ++s)
                        Ep[(long)(rowbw + tm * 32 + q * 8 + s) * ldc + col] = us[q * 4 + s];
                    pk[tn][q * 2 + 0] = (uint)us[q * 4 + 0] | ((uint)us[q * 4 + 1] << 16);
                    pk[tn][q * 2 + 1] = (uint)us[q * 4 + 2] | ((uint)us[q * 4 + 3] << 16);
                }
            }
            // merged ET stores: one full 64B line per lane per tm (lh==tn writes)
            #pragma unroll
            for (int tn = 0; tn < 2; ++tn)
                #pragma unroll
                for (int q = 0; q < 4; ++q) {
                    const uint ox = __shfl_xor(pk[tn][q * 2 + 0], 32);
                    const uint oy = __shfl_xor(pk[tn][q * 2 + 1], 32);
                    if (lh == tn) {
                        const uint4 v = (lh == 0)
                            ? make_uint4(pk[tn][q * 2], pk[tn][q * 2 + 1], ox, oy)
                            : make_uint4(ox, oy, pk[tn][q * 2], pk[tn][q * 2 + 1]);
                        const int grm = m0 + wr * 64 + tm * 32 + q * 8;
                        const int col = colb0 + tn * 32;
                        *(uint4*)&ETp[(long)col * ldct + grm] = v;
                    }
                }
            #pragma unroll
            for (int rr = 0; rr < 16; ++rr) {
                float v = rowp[rr];
                v += __shfl_xor(v, 1);  v += __shfl_xor(v, 2);
                v += __shfl_xor(v, 4);  v += __shfl_xor(v, 8);
                v += __shfl_xor(v, 16);
                if (lr == 0)
                    atomicAdd(&rs[rowbw + tm * 32 + (rr & 3) + 8 * (rr >> 2)], v);
            }
        }
        #pragma unroll
        for (int tn = 0; tn < 2; ++tn) {
            float v = colp[tn];
            v += __shfl_xor(v, 32);
            if (lh == 0) atomicAdd(&cs[colb0 + tn * 32], v);
        }
    } else { // MODE == 2
        const float* sc = (sec ? scale2_ : scale_) + zl * sSum;
        ushort* Cp = (ushort*)(sec ? Cptr2_ : Cptr_) + zl * sC;
        #pragma unroll
        for (int tm = 0; tm < 2; ++tm) {
            float rcp[16];
            #pragma unroll
            for (int rr = 0; rr < 16; ++rr)
                rcp[rr] = 1.f / sc[rowbw + tm * 32 + (rr & 3) + 8 * (rr >> 2)];
            #pragma unroll
            for (int tn = 0; tn < 2; ++tn) {
                const int col = colb0 + tn * 32;
                #pragma unroll
                for (int q = 0; q < 4; ++q)
                    #pragma unroll
                    for (int s = 0; s < 4; ++s)
                        Cp[(long)(rowbw + tm * 32 + q * 8 + s) * ldc + col] =
                            f2bf(acc[tm][tn][q * 4 + s] * rcp[q * 4 + s]);
            }
        }
    }
}

// f32 -> bf16 elementwise (vectorized 8/thread, grid-stride)
__global__ __launch_bounds__(256)
void cast32to16(const float* __restrict__ in, ushort* __restrict__ out, long n) {
    const long stride = (long)gridDim.x * 256 * 8;
    for (long i = ((long)blockIdx.x * 256 + threadIdx.x) * 8; i < n; i += stride) {
        const float4 f0 = *(const float4*)(in + i);
        const float4 f1 = *(const float4*)(in + i + 4);
        uint4 w;
        w.x = (uint)f2bf(f0.x) | ((uint)f2bf(f0.y) << 16);
        w.y = (uint)f2bf(f0.z) | ((uint)f2bf(f0.w) << 16);
        w.z = (uint)f2bf(f1.x) | ((uint)f2bf(f1.y) << 16);
        w.w = (uint)f2bf(f1.z) | ((uint)f2bf(f1.w) << 16);
        *(uint4*)(out + i) = w;
    }
}

// f32 [R][C] -> bf16 [C][R]
__global__ __launch_bounds__(256)
void tcast(const float* __restrict__ in, ushort* __restrict__ out, int R, int C) {
    __shared__ float t[32][33];
    const int bx = blockIdx.x * 32, by = blockIdx.y * 32;
    const int tx = threadIdx.x, ty = threadIdx.y; // (32, 8)
    for (int i = ty; i < 32; i += 8) {
        const int r = by + i, cc = bx + tx;
        if (r < R && cc < C) t[i][tx] = in[(long)r * C + cc];
    }
    __syncthreads();
    for (int i = ty; i < 32; i += 8) {
        const int cc = bx + i, r = by + tx;
        if (cc < C && r < R) out[(long)cc * R + r] = f2bf(t[tx][i]);
    }
}

// LayerNorm: bf16 input row -> f32 output row. D/4 threads, one row per block.
template<int D>
__global__ __launch_bounds__(D / 4)
void ln_bf(const ushort* __restrict__ y, float* __restrict__ out,
           const float* __restrict__ gam, const float* __restrict__ bet) {
    constexpr int NW = D / 256;   // waves per block (3 for 768, 2 for 512)
    const long row = blockIdx.x;
    const int tid = threadIdx.x;
    const ushort4 v4 = *(const ushort4*)&y[row * D + tid * 4];
    float v[4] = {bf2f(v4.x), bf2f(v4.y), bf2f(v4.z), bf2f(v4.w)};
    float s = v[0] + v[1] + v[2] + v[3];
    float s2 = v[0]*v[0] + v[1]*v[1] + v[2]*v[2] + v[3]*v[3];
    #pragma unroll
    for (int off = 1; off < 64; off <<= 1) {
        s  += __shfl_xor(s, off);
        s2 += __shfl_xor(s2, off);
    }
    __shared__ float ws[4], ws2[4];
    const int wave = tid >> 6, lane = tid & 63;
    if (lane == 0) { ws[wave] = s; ws2[wave] = s2; }
    __syncthreads();
    s = 0.f; s2 = 0.f;
    #pragma unroll
    for (int w2 = 0; w2 < NW; ++w2) { s += ws[w2]; s2 += ws2[w2]; }
    const float mu   = s / D;
    const float var  = s2 / D - mu * mu;
    const float rstd = rsqrtf(var + 1e-5f);
    const float4 gv = *(const float4*)&gam[tid * 4];
    const float4 bv = *(const float4*)&bet[tid * 4];
    float4 o;
    o.x = (v[0] - mu) * rstd * gv.x + bv.x;
    o.y = (v[1] - mu) * rstd * gv.y + bv.y;
    o.z = (v[2] - mu) * rstd * gv.z + bv.z;
    o.w = (v[3] - mu) * rstd * gv.w + bv.w;
    *(float4*)&out[row * D + tid * 4] = o;
}

extern "C" void kernel_launch(void* const* d_in, const int* in_sizes, int n_in,
                              void* d_out, int out_size, void* d_ws, size_t ws_size,
                              hipStream_t stream)
{
    (void)in_sizes; (void)n_in; (void)out_size; (void)ws_size;
    const float* z_a    = (const float*)d_in[0];
    const float* z_b    = (const float*)d_in[1];
    const float* Wa     = (const float*)d_in[2];
    const float* ba     = (const float*)d_in[3];
    const float* Wb     = (const float*)d_in[4];
    const float* bb     = (const float*)d_in[5];
    const float* Wco    = (const float*)d_in[6];
    const float* Woa    = (const float*)d_in[7];
    const float* boa    = (const float*)d_in[8];
    const float* Wob    = (const float*)d_in[9];
    const float* bob    = (const float*)d_in[10];
    const float* ga     = (const float*)d_in[11];
    const float* beta_a = (const float*)d_in[12];
    const float* gb     = (const float*)d_in[13];
    const float* beta_b = (const float*)d_in[14];

    const int Bn = 16, LA = 2048, LB = 2048, DA = 768, DB = 512, DH = 512;
    const int ZC = 8;                      // batches per chunk (E/ET L3-resident)
    const long MA = (long)Bn * LA;
    const long MB = (long)Bn * LB;

    char* w = (char*)d_ws;
    size_t off = 0;
    auto alc = [&](size_t bytes) { void* p = w + off; off += (bytes + 255) & ~(size_t)255; return p; };

    ushort* WaT  = (ushort*)alc((size_t)DH * DA * 2);
    ushort* WbT  = (ushort*)alc((size_t)DH * DB * 2);
    ushort* WcoT = (ushort*)alc((size_t)DH * DH * 2);
    ushort* WoaT = (ushort*)alc((size_t)DA * DH * 2);
    ushort* WobT = (ushort*)alc((size_t)DB * DH * 2);
    ushort* h_a  = (ushort*)alc((size_t)MA * DH * 2);
    ushort* h_b  = (ushort*)alc((size_t)MB * DH * 2);
    ushort* h_aT = (ushort*)alc((size_t)Bn * DH * LA * 2);
    ushort* h_bT = (ushort*)alc((size_t)Bn * DH * LB * 2);
    ushort* Ma   = (ushort*)alc((size_t)MA * DH * 2);
    ushort* E    = (ushort*)alc((size_t)ZC * LA * LB * 2);   // chunk-sized, reused
    ushort* ET   = (ushort*)alc((size_t)ZC * LB * LA * 2);   // chunk-sized, reused
    ushort* Pa   = (ushort*)alc((size_t)MA * DH * 2);
    ushort* Pb   = (ushort*)alc((size_t)MB * DH * 2);
    float*  rsum = (float*)alc((size_t)Bn * LA * 4);
    float*  csum = (float*)alc((size_t)Bn * LB * 4);

    // bf16 residuals in d_out scratch (dead before LN overwrites — proven r9/r10)
    ushort* za16 = (ushort*)d_out;
    ushort* zb16 = za16 + (size_t)MA * DA;
    // pre-LN bf16 y in E/ET regions (dead after last PaPb chunk)
    ushort* yA = E;
    ushort* yB = E + (size_t)MA * DA;

    dim3 blk(1024, 1, 1);
    dim3 blk256(256, 1, 1);
    dim3 tb(32, 8, 1);
    const int SHM = 2 * BUF_U * 2;   // 131072 B dynamic LDS
    const int NOSPLIT = 1 << 30;

    // weight transposes (f32 -> bf16, [K][N] -> [N][K])
    tcast<<<dim3(DH / 32, DA / 32, 1), tb, 0, stream>>>(Wa,  WaT,  DA, DH);
    tcast<<<dim3(DH / 32, DB / 32, 1), tb, 0, stream>>>(Wb,  WbT,  DB, DH);
    tcast<<<dim3(DH / 32, DH / 32, 1), tb, 0, stream>>>(Wco, WcoT, DH, DH);
    tcast<<<dim3(DA / 32, DH / 32, 1), tb, 0, stream>>>(Woa, WoaT, DH, DA);
    tcast<<<dim3(DB / 32, DH / 32, 1), tb, 0, stream>>>(Wob, WobT, DH, DB);

    // activations f32 -> bf16 (into d_out scratch)
    cast32to16<<<dim3(2048, 1, 1), blk256, 0, stream>>>(z_a, za16, MA * DA);
    cast32to16<<<dim3(2048, 1, 1), blk256, 0, stream>>>(z_b, zb16, MB * DB);

    // zero softmax denominators (rsum & csum are contiguous)
    hipMemsetAsync(rsum, 0, (size_t)Bn * (LA + LB) * sizeof(float), stream);

    // h_a = z_a @ Wa + ba   (also writes h_aT per batch)
    gemm_bt<0, true, true><<<dim3(MA / BM, DH / BN, 1), blk, SHM, stream>>>(
        za16, WaT, h_a, h_aT, ba, nullptr, nullptr, nullptr, nullptr,
        nullptr, nullptr, nullptr, nullptr, NOSPLIT,
        (int)MA, DH, DA, DA, DA, DH, 0, 0, 0, (long)DH * LA, 0, LA, 11);

    // h_b = z_b @ Wb + bb   (also writes h_bT per batch)
    gemm_bt<0, true, true><<<dim3(MB / BM, DH / BN, 1), blk, SHM, stream>>>(
        zb16, WbT, h_b, h_bT, bb, nullptr, nullptr, nullptr, nullptr,
        nullptr, nullptr, nullptr, nullptr, NOSPLIT,
        (int)MB, DH, DB, DB, DB, DH, 0, 0, 0, (long)DH * LB, 0, LB, 11);

    // Ma = h_a @ W_co
    gemm_bt<0, false, false><<<dim3(MA / BM, DH / BN, 1), blk, SHM, stream>>>(
        h_a, WcoT, Ma, nullptr, nullptr, nullptr, nullptr, nullptr, nullptr,
        nullptr, nullptr, nullptr, nullptr, NOSPLIT,
        (int)MA, DH, DH, DH, DH, DH, 0, 0, 0, 0, 0, 0, 0);

    // ---- chunked scores -> (Pa | Pb) with L3-resident E/ET reuse ----
    for (int c = 0; c < Bn / ZC; ++c) {
        const ushort* Ma_c  = Ma   + (size_t)c * ZC * LA * DH;
        const ushort* hb_c  = h_b  + (size_t)c * ZC * LB * DH;
        const ushort* hbT_c = h_bT + (size_t)c * ZC * DH * LB;
        const ushort* haT_c = h_aT + (size_t)c * ZC * DH * LA;
        ushort* Pa_c = Pa + (size_t)c * ZC * LA * DH;
        ushort* Pb_c = Pb + (size_t)c * ZC * LB * DH;
        float* rs_c = rsum + (size_t)c * ZC * LA;
        float* cs_c = csum + (size_t)c * ZC * LB;

        // scores chunk: E = exp(tanh(Ma_c @ h_b_c^T)), E^T, rowsum, colsum
        gemm_bt<1, false, false><<<dim3(LA / BM, LB / BN, ZC), blk, SHM, stream>>>(
            Ma_c, hb_c, E, ET, nullptr, nullptr, rs_c, cs_c, nullptr,
            nullptr, nullptr, nullptr, nullptr, NOSPLIT,
            LA, LB, DH, DH, DH, LB,
            (long)LA * DH, (long)LB * DH, (long)LA * LB, (long)LB * LA, LA, LA, 0);

        // fused: z<ZC -> Pa_c = (E @ h_bT_c)/rsum ; z>=ZC -> Pb_c = (ET @ h_aT_c)/csum
        gemm_bt<2, false, false><<<dim3(LA / BM, DH / BN, 2 * ZC), blk, SHM, stream>>>(
            E, hbT_c, Pa_c, nullptr, nullptr, nullptr, nullptr, nullptr, rs_c,
            ET, haT_c, Pb_c, cs_c, ZC,
            LA, DH, LB, LB, LB, DH,
            (long)LA * LB, (long)DH * LB, (long)LA * DH, 0, LA, 0, 0);
    }

    // yA = bf16(Pa @ Woa + boa + z_a), yB = bf16(Pb @ Wob + bob + z_b)
    gemm_bt<3, true, false><<<dim3(MA / BM, DA / BN, 1), blk, SHM, stream>>>(
        Pa, WoaT, yA, nullptr, boa, za16, nullptr, nullptr, nullptr,
        nullptr, nullptr, nullptr, nullptr, NOSPLIT,
        (int)MA, DA, DH, DH, DH, DA, 0, 0, 0, 0, 0, 0, 0);

    gemm_bt<3, true, false><<<dim3(MB / BM, DB / BN, 1), blk, SHM, stream>>>(
        Pb, WobT, yB, nullptr, bob, zb16, nullptr, nullptr, nullptr,
        nullptr, nullptr, nullptr, nullptr, NOSPLIT,
        (int)MB, DB, DH, DH, DH, DB, 0, 0, 0, 0, 0, 0, 0);

    // LayerNorms: bf16 y -> f32 d_out (overwrites za16/zb16 scratch, now dead)
    float* outA = (float*)d_out;
    float* outB = outA + MA * DA;
    ln_bf<768><<<dim3((unsigned)MA, 1, 1), dim3(192, 1, 1), 0, stream>>>(yA, outA, ga, beta_a);
    ln_bf<512><<<dim3((unsigned)MB, 1, 1), dim3(128, 1, 1), 0, stream>>>(yB, outB, gb, beta_b);
}

// Round 16
// 652.309 us; speedup vs baseline: 1.0202x; 1.0202x over previous
//
#include <hip/hip_runtime.h>
#include <stdint.h>

typedef short bf16x8 __attribute__((ext_vector_type(8)));
typedef float f32x16 __attribute__((ext_vector_type(16)));

#define BM 256
#define BN 256
#define BK 64
#define ABUF_U 16384   // 256*64 ushorts (32KB) A region
#define BUF_U  32768   // A+B per buffer in ushorts (64KB); 2 buffers = 128KB

#define AS1 __attribute__((address_space(1)))
#define AS3 __attribute__((address_space(3)))

__device__ __forceinline__ ushort f2bf(float x) {
    uint32_t u = __float_as_uint(x);
    u += 0x7FFFu + ((u >> 16) & 1u);
    return (ushort)(u >> 16);
}
__device__ __forceinline__ float bf2f(ushort u) {
    return __uint_as_float((uint)u << 16);
}

__device__ __forceinline__ void gload16(const void* g, void* l) {
    __builtin_amdgcn_global_load_lds((const AS1 void*)g, (AS3 void*)l, 16, 0, 0);
}

// issue 2 staging loads (chunks i0, i0+1 of 8) for K-offset kt into buffer buf
#define ISSUE2(kt, buf, i0)                                                          \
    do {                                                                             \
        gload16(((i0) < 4 ? Ap : Bp) + goff[i0] + (kt), smem + (buf)*BUF_U + loff[i0]); \
        gload16((((i0)+1) < 4 ? Ap : Bp) + goff[(i0)+1] + (kt), smem + (buf)*BUF_U + loff[(i0)+1]); \
    } while (0)

// C[M,N] = A[M,K] * B[N,K]^T, bf16 MFMA 32x32x16.  (r12 structure — champion)
// 256x256 tile, 512 threads (8 waves: 2M x 4N, per-wave 128x64 = 4x2 32x32 tiles).
// K-loop: 2 barriers/tile; interior (24 ds_read_b128 + 32 MFMA + 6 prefetch gloads)
// left to compiler lgkmcnt pipelining. Counted vmcnt(2)/tile.
// 32x32 C/D layout -> full-line coalesced row-major stores. XCD swizzle (m204).
// Dual pointer sets: blocks with z >= zsplit use the *2 pointers with local
// batch zl = z - zsplit (lets Pa and Pb share one full-GPU MODE-2 launch).
// MODE 0: bf16 out = acc (+bias), optional transposed copy (per-batch [col][row])
// MODE 1: scores: e=exp(tanh(acc)); write E + E^T bf16; atomic rowsum/colsum
// MODE 2: bf16 out = acc / scale[row]
// MODE 3: bf16 out = acc + bias[col] + bf16 resid[row,col]   (pre-LN tensor)
template<int MODE, bool HAS_BIAS, bool WRITE_T>
__global__ __launch_bounds__(512, 2)
void gemm_bt(const ushort* __restrict__ Aptr_, const ushort* __restrict__ Bptr_,
             void* __restrict__ Cptr_, ushort* __restrict__ CTptr_,
             const float* __restrict__ bias, const ushort* __restrict__ resid_,
             float* __restrict__ rsum_, float* __restrict__ csum_,
             const float* __restrict__ scale_,
             const ushort* __restrict__ Aptr2_, const ushort* __restrict__ Bptr2_,
             void* __restrict__ Cptr2_, const float* __restrict__ scale2_, int zsplit,
             int M, int N, int K, int lda, int ldb, int ldc,
             long sA, long sB, long sC, long sCT, long sSum,
             int ldct, int rbshift)
{
    extern __shared__ ushort smem[];   // 2 * BUF_U ushorts (128KB)

    // ---- bijective XCD swizzle (T1, m204) ----
    const int gx = gridDim.x, gy = gridDim.y;
    const int nwg = gx * gy * (int)gridDim.z;
    int flat = ((int)blockIdx.z * gy + (int)blockIdx.y) * gx + (int)blockIdx.x;
    {
        const int q8 = nwg >> 3, r8 = nwg & 7;
        const int xcd = flat & 7, loc = flat >> 3;
        flat = (xcd < r8 ? xcd * (q8 + 1) : r8 * (q8 + 1) + (xcd - r8) * q8) + loc;
    }
    const int z   = flat / (gx * gy);
    const int rem = flat - z * (gx * gy);
    const int m0  = (rem % gx) * BM;
    const int n0  = (rem / gx) * BN;

    const bool sec = (z >= zsplit);
    const int  zl  = sec ? z - zsplit : z;

    const int tid  = threadIdx.x;
    const int lane = tid & 63;
    const int wave = tid >> 6;
    const int wr   = wave >> 2;        // 0..1 -> rows wr*128..+128
    const int wcn  = wave & 3;         // 0..3 -> cols wcn*64..+64
    const int lr   = lane & 31, lh = lane >> 5;

    const ushort* Ap = (sec ? Aptr2_ : Aptr_) + (long)zl * sA;
    const ushort* Bp = (sec ? Bptr2_ : Bptr_) + (long)zl * sB;

    // staging: linear LDS dest, XOR-swizzled global source chunk (both-sides).
    long goff[8]; int loff[8];
    #pragma unroll
    for (int u = 0; u < 4; ++u) {
        const int li  = u * 512 + tid;       // chunk 0..2047 (A and B each)
        const int row = li >> 3;             // 0..255
        const int gck = (li & 7) ^ (row & 7);
        goff[u]     = (long)(m0 + row) * lda + gck * 8;
        loff[u]     = li * 8;
        goff[u + 4] = (long)(n0 + row) * ldb + gck * 8;
        loff[u + 4] = ABUF_U + li * 8;
    }

    f32x16 acc[4][2] = {};

    const int nk = K / BK;
    // prologue: stage tile 0 into buf 0 (8 loads/thread)
    ISSUE2(0, 0, 0); ISSUE2(0, 0, 2); ISSUE2(0, 0, 4); ISSUE2(0, 0, 6);

    for (int t = 0; t < nk; ++t) {
        const int cur = t & 1, nxt = cur ^ 1;
        const ushort* As = smem + cur * BUF_U;
        const ushort* Bs = As + ABUF_U;
        const bool pf = (t + 1 < nk);
        const int kt1 = (t + 1) * BK;

        if (pf) {
            ISSUE2(kt1, nxt, 0);
            asm volatile("s_waitcnt vmcnt(2)" ::: "memory");  // tile t landed; 2 prefetch in flight
        } else {
            asm volatile("s_waitcnt vmcnt(0)" ::: "memory");  // tail drain
        }
        __builtin_amdgcn_s_barrier();

        // tile interior: no manual fences — compiler pipelines ds_read vs MFMA
        #pragma unroll
        for (int kk = 0; kk < 4; ++kk) {          // 4 k-steps of 16
            bf16x8 af[4], bfv[2];
            #pragma unroll
            for (int tm = 0; tm < 4; ++tm) {
                const int row = wr * 128 + tm * 32 + lr;
                const int ck  = (kk * 2 + lh) ^ (row & 7);
                af[tm] = *(const bf16x8*)&As[row * BK + ck * 8];
            }
            #pragma unroll
            for (int tn = 0; tn < 2; ++tn) {
                const int row = wcn * 64 + tn * 32 + lr;
                const int ck  = (kk * 2 + lh) ^ (row & 7);
                bfv[tn] = *(const bf16x8*)&Bs[row * BK + ck * 8];
            }
            if (pf) {
                if (kk == 0)      ISSUE2(kt1, nxt, 2);
                else if (kk == 1) ISSUE2(kt1, nxt, 4);
                else if (kk == 2) ISSUE2(kt1, nxt, 6);
            }
            #pragma unroll
            for (int tm = 0; tm < 4; ++tm)
                #pragma unroll
                for (int tn = 0; tn < 2; ++tn)
                    acc[tm][tn] = __builtin_amdgcn_mfma_f32_32x32x16_bf16(
                        af[tm], bfv[tn], acc[tm][tn], 0, 0, 0);
        }

        asm volatile("s_waitcnt lgkmcnt(0)" ::: "memory");  // my reads of cur done
        __builtin_amdgcn_s_barrier();                        // all waves done -> cur reusable
    }

    // ---- epilogues (direct stores; 32x32 layout -> full-line coalescing) ----
    const int colb0 = n0 + wcn * 64 + lr;         // tn=0 col
    const int rowbw = m0 + wr * 128 + 4 * lh;     // + tm*32 + q*8 + s

    if constexpr (MODE == 3) {
        ushort* Cp = (ushort*)Cptr_;
        #pragma unroll
        for (int tm = 0; tm < 4; ++tm)
            #pragma unroll
            for (int tn = 0; tn < 2; ++tn) {
                const int col = colb0 + tn * 32;
                const float bv = bias[col];
                #pragma unroll
                for (int q = 0; q < 4; ++q)
                    #pragma unroll
                    for (int s = 0; s < 4; ++s) {
                        const int row = rowbw + tm * 32 + q * 8 + s;
                        const long idx = (long)row * ldc + col;
                        Cp[idx] = f2bf(acc[tm][tn][q * 4 + s] + bv + bf2f(resid_[idx]));
                    }
            }
    } else if constexpr (MODE == 0) {
        ushort* Cp = (ushort*)Cptr_ + zl * sC;
        #pragma unroll
        for (int tm = 0; tm < 4; ++tm)
            #pragma unroll
            for (int tn = 0; tn < 2; ++tn) {
                const int col = colb0 + tn * 32;
                const float bv = HAS_BIAS ? bias[col] : 0.f;
                ushort us[16];
                #pragma unroll
                for (int rr = 0; rr < 16; ++rr) us[rr] = f2bf(acc[tm][tn][rr] + bv);
                #pragma unroll
                for (int q = 0; q < 4; ++q)
                    #pragma unroll
                    for (int s = 0; s < 4; ++s)
                        Cp[(long)(rowbw + tm * 32 + q * 8 + s) * ldc + col] = us[q * 4 + s];
                if constexpr (WRITE_T) {
                    #pragma unroll
                    for (int q = 0; q < 4; ++q) {
                        const int gr = rowbw + tm * 32 + q * 8;
                        const int bb = gr >> rbshift;
                        const int ii = gr & ((1 << rbshift) - 1);
                        *(ushort4*)&CTptr_[(long)bb * sCT + (long)col * ldct + ii] =
                            make_ushort4(us[q * 4 + 0], us[q * 4 + 1], us[q * 4 + 2], us[q * 4 + 3]);
                    }
                }
            }
    } else if constexpr (MODE == 1) {
        ushort* Ep  = (ushort*)Cptr_ + zl * sC;
        ushort* ETp = CTptr_ + zl * sCT;
        float* rs = rsum_ + zl * sSum;
        float* cs = csum_ + zl * sSum;
        float colp[2] = {0.f, 0.f};
        #pragma unroll
        for (int tm = 0; tm < 4; ++tm) {
            float rowp[16];
            #pragma unroll
            for (int rr = 0; rr < 16; ++rr) rowp[rr] = 0.f;
            #pragma unroll
            for (int tn = 0; tn < 2; ++tn) {
                const int col = colb0 + tn * 32;
                ushort us[16];
                #pragma unroll
                for (int rr = 0; rr < 16; ++rr) {
                    const float x  = acc[tm][tn][rr];
                    const float th = 1.f - 2.f / (__expf(2.f * x) + 1.f);  // tanh(x)
                    const float e  = __expf(th);
                    rowp[rr] += e;
                    colp[tn] += e;
                    us[rr] = f2bf(e);
                }
                #pragma unroll
                for (int q = 0; q < 4; ++q) {
                    #pragma unroll
                    for (int s = 0; s < 4; ++s)
                        Ep[(long)(rowbw + tm * 32 + q * 8 + s) * ldc + col] = us[q * 4 + s];
                    const int gr = rowbw + tm * 32 + q * 8;
                    *(ushort4*)&ETp[(long)col * ldct + gr] =
                        make_ushort4(us[q * 4 + 0], us[q * 4 + 1], us[q * 4 + 2], us[q * 4 + 3]);
                }
            }
            #pragma unroll
            for (int rr = 0; rr < 16; ++rr) {
                float v = rowp[rr];
                v += __shfl_xor(v, 1);  v += __shfl_xor(v, 2);
                v += __shfl_xor(v, 4);  v += __shfl_xor(v, 8);
                v += __shfl_xor(v, 16);
                if (lr == 0)
                    atomicAdd(&rs[rowbw + tm * 32 + (rr & 3) + 8 * (rr >> 2)], v);
            }
        }
        #pragma unroll
        for (int tn = 0; tn < 2; ++tn) {
            float v = colp[tn];
            v += __shfl_xor(v, 32);
            if (lh == 0) atomicAdd(&cs[colb0 + tn * 32], v);
        }
    } else { // MODE == 2
        const float* sc = (sec ? scale2_ : scale_) + zl * sSum;
        ushort* Cp = (ushort*)(sec ? Cptr2_ : Cptr_) + zl * sC;
        #pragma unroll
        for (int tm = 0; tm < 4; ++tm) {
            float rcp[16];
            #pragma unroll
            for (int rr = 0; rr < 16; ++rr)
                rcp[rr] = 1.f / sc[rowbw + tm * 32 + (rr & 3) + 8 * (rr >> 2)];
            #pragma unroll
            for (int tn = 0; tn < 2; ++tn) {
                const int col = colb0 + tn * 32;
                #pragma unroll
                for (int q = 0; q < 4; ++q)
                    #pragma unroll
                    for (int s = 0; s < 4; ++s)
                        Cp[(long)(rowbw + tm * 32 + q * 8 + s) * ldc + col] =
                            f2bf(acc[tm][tn][q * 4 + s] * rcp[q * 4 + s]);
            }
        }
    }
}

// f32 -> bf16 elementwise (vectorized 8/thread, grid-stride)
__global__ __launch_bounds__(256)
void cast32to16(const float* __restrict__ in, ushort* __restrict__ out, long n) {
    const long stride = (long)gridDim.x * 256 * 8;
    for (long i = ((long)blockIdx.x * 256 + threadIdx.x) * 8; i < n; i += stride) {
        const float4 f0 = *(const float4*)(in + i);
        const float4 f1 = *(const float4*)(in + i + 4);
        uint4 w;
        w.x = (uint)f2bf(f0.x) | ((uint)f2bf(f0.y) << 16);
        w.y = (uint)f2bf(f0.z) | ((uint)f2bf(f0.w) << 16);
        w.z = (uint)f2bf(f1.x) | ((uint)f2bf(f1.y) << 16);
        w.w = (uint)f2bf(f1.z) | ((uint)f2bf(f1.w) << 16);
        *(uint4*)(out + i) = w;
    }
}

// f32 [R][C] -> bf16 [C][R]
__global__ __launch_bounds__(256)
void tcast(const float* __restrict__ in, ushort* __restrict__ out, int R, int C) {
    __shared__ float t[32][33];
    const int bx = blockIdx.x * 32, by = blockIdx.y * 32;
    const int tx = threadIdx.x, ty = threadIdx.y; // (32, 8)
    for (int i = ty; i < 32; i += 8) {
        const int r = by + i, cc = bx + tx;
        if (r < R && cc < C) t[i][tx] = in[(long)r * C + cc];
    }
    __syncthreads();
    for (int i = ty; i < 32; i += 8) {
        const int cc = bx + i, r = by + tx;
        if (cc < C && r < R) out[(long)cc * R + r] = f2bf(t[tx][i]);
    }
}

// LayerNorm: bf16 input row -> f32 output row. D/4 threads, one row per block.
template<int D>
__global__ __launch_bounds__(D / 4)
void ln_bf(const ushort* __restrict__ y, float* __restrict__ out,
           const float* __restrict__ gam, const float* __restrict__ bet) {
    constexpr int NW = D / 256;   // waves per block (3 for 768, 2 for 512)
    const long row = blockIdx.x;
    const int tid = threadIdx.x;
    const ushort4 v4 = *(const ushort4*)&y[row * D + tid * 4];
    float v[4] = {bf2f(v4.x), bf2f(v4.y), bf2f(v4.z), bf2f(v4.w)};
    float s = v[0] + v[1] + v[2] + v[3];
    float s2 = v[0]*v[0] + v[1]*v[1] + v[2]*v[2] + v[3]*v[3];
    #pragma unroll
    for (int off = 1; off < 64; off <<= 1) {
        s  += __shfl_xor(s, off);
        s2 += __shfl_xor(s2, off);
    }
    __shared__ float ws[4], ws2[4];
    const int wave = tid >> 6, lane = tid & 63;
    if (lane == 0) { ws[wave] = s; ws2[wave] = s2; }
    __syncthreads();
    s = 0.f; s2 = 0.f;
    #pragma unroll
    for (int w2 = 0; w2 < NW; ++w2) { s += ws[w2]; s2 += ws2[w2]; }
    const float mu   = s / D;
    const float var  = s2 / D - mu * mu;
    const float rstd = rsqrtf(var + 1e-5f);
    const float4 gv = *(const float4*)&gam[tid * 4];
    const float4 bv = *(const float4*)&bet[tid * 4];
    float4 o;
    o.x = (v[0] - mu) * rstd * gv.x + bv.x;
    o.y = (v[1] - mu) * rstd * gv.y + bv.y;
    o.z = (v[2] - mu) * rstd * gv.z + bv.z;
    o.w = (v[3] - mu) * rstd * gv.w + bv.w;
    *(float4*)&out[row * D + tid * 4] = o;
}

extern "C" void kernel_launch(void* const* d_in, const int* in_sizes, int n_in,
                              void* d_out, int out_size, void* d_ws, size_t ws_size,
                              hipStream_t stream)
{
    (void)in_sizes; (void)n_in; (void)out_size; (void)ws_size;
    const float* z_a    = (const float*)d_in[0];
    const float* z_b    = (const float*)d_in[1];
    const float* Wa     = (const float*)d_in[2];
    const float* ba     = (const float*)d_in[3];
    const float* Wb     = (const float*)d_in[4];
    const float* bb     = (const float*)d_in[5];
    const float* Wco    = (const float*)d_in[6];
    const float* Woa    = (const float*)d_in[7];
    const float* boa    = (const float*)d_in[8];
    const float* Wob    = (const float*)d_in[9];
    const float* bob    = (const float*)d_in[10];
    const float* ga     = (const float*)d_in[11];
    const float* beta_a = (const float*)d_in[12];
    const float* gb     = (const float*)d_in[13];
    const float* beta_b = (const float*)d_in[14];

    const int Bn = 16, LA = 2048, LB = 2048, DA = 768, DB = 512, DH = 512;
    const int ZC = 8;                      // batches per chunk (E/ET L3-resident)
    const long MA = (long)Bn * LA;
    const long MB = (long)Bn * LB;

    char* w = (char*)d_ws;
    size_t off = 0;
    auto alc = [&](size_t bytes) { void* p = w + off; off += (bytes + 255) & ~(size_t)255; return p; };

    ushort* WaT  = (ushort*)alc((size_t)DH * DA * 2);
    ushort* WbT  = (ushort*)alc((size_t)DH * DB * 2);
    ushort* WcoT = (ushort*)alc((size_t)DH * DH * 2);
    ushort* WoaT = (ushort*)alc((size_t)DA * DH * 2);
    ushort* WobT = (ushort*)alc((size_t)DB * DH * 2);
    ushort* h_a  = (ushort*)alc((size_t)MA * DH * 2);
    ushort* h_b  = (ushort*)alc((size_t)MB * DH * 2);
    ushort* h_aT = (ushort*)alc((size_t)Bn * DH * LA * 2);
    ushort* h_bT = (ushort*)alc((size_t)Bn * DH * LB * 2);
    ushort* Ma   = (ushort*)alc((size_t)MA * DH * 2);
    ushort* E    = (ushort*)alc((size_t)ZC * LA * LB * 2);   // chunk-sized, reused
    ushort* ET   = (ushort*)alc((size_t)ZC * LB * LA * 2);   // chunk-sized, reused
    ushort* Pa   = (ushort*)alc((size_t)MA * DH * 2);
    ushort* Pb   = (ushort*)alc((size_t)MB * DH * 2);
    float*  rsum = (float*)alc((size_t)Bn * LA * 4);
    float*  csum = (float*)alc((size_t)Bn * LB * 4);

    // bf16 residuals in d_out scratch (dead before LN overwrites — proven r9/r10)
    ushort* za16 = (ushort*)d_out;
    ushort* zb16 = za16 + (size_t)MA * DA;
    // pre-LN bf16 y in E/ET regions (dead after last PaPb chunk)
    ushort* yA = E;
    ushort* yB = E + (size_t)MA * DA;

    dim3 blk(512, 1, 1);
    dim3 blk256(256, 1, 1);
    dim3 tb(32, 8, 1);
    const int SHM = 2 * BUF_U * 2;   // 131072 B dynamic LDS
    const int NOSPLIT = 1 << 30;

    // weight transposes (f32 -> bf16, [K][N] -> [N][K])
    tcast<<<dim3(DH / 32, DA / 32, 1), tb, 0, stream>>>(Wa,  WaT,  DA, DH);
    tcast<<<dim3(DH / 32, DB / 32, 1), tb, 0, stream>>>(Wb,  WbT,  DB, DH);
    tcast<<<dim3(DH / 32, DH / 32, 1), tb, 0, stream>>>(Wco, WcoT, DH, DH);
    tcast<<<dim3(DA / 32, DH / 32, 1), tb, 0, stream>>>(Woa, WoaT, DH, DA);
    tcast<<<dim3(DB / 32, DH / 32, 1), tb, 0, stream>>>(Wob, WobT, DH, DB);

    // activations f32 -> bf16 (into d_out scratch)
    cast32to16<<<dim3(2048, 1, 1), blk256, 0, stream>>>(z_a, za16, MA * DA);
    cast32to16<<<dim3(2048, 1, 1), blk256, 0, stream>>>(z_b, zb16, MB * DB);

    // zero softmax denominators (rsum & csum are contiguous)
    hipMemsetAsync(rsum, 0, (size_t)Bn * (LA + LB) * sizeof(float), stream);

    // h_a = z_a @ Wa + ba   (also writes h_aT per batch)
    gemm_bt<0, true, true><<<dim3(MA / BM, DH / BN, 1), blk, SHM, stream>>>(
        za16, WaT, h_a, h_aT, ba, nullptr, nullptr, nullptr, nullptr,
        nullptr, nullptr, nullptr, nullptr, NOSPLIT,
        (int)MA, DH, DA, DA, DA, DH, 0, 0, 0, (long)DH * LA, 0, LA, 11);

    // h_b = z_b @ Wb + bb   (also writes h_bT per batch)
    gemm_bt<0, true, true><<<dim3(MB / BM, DH / BN, 1), blk, SHM, stream>>>(
        zb16, WbT, h_b, h_bT, bb, nullptr, nullptr, nullptr, nullptr,
        nullptr, nullptr, nullptr, nullptr, NOSPLIT,
        (int)MB, DH, DB, DB, DB, DH, 0, 0, 0, (long)DH * LB, 0, LB, 11);

    // Ma = h_a @ W_co
    gemm_bt<0, false, false><<<dim3(MA / BM, DH / BN, 1), blk, SHM, stream>>>(
        h_a, WcoT, Ma, nullptr, nullptr, nullptr, nullptr, nullptr, nullptr,
        nullptr, nullptr, nullptr, nullptr, NOSPLIT,
        (int)MA, DH, DH, DH, DH, DH, 0, 0, 0, 0, 0, 0, 0);

    // ---- chunked scores -> (Pa | Pb) with L3-resident E/ET reuse ----
    for (int c = 0; c < Bn / ZC; ++c) {
        const ushort* Ma_c  = Ma   + (size_t)c * ZC * LA * DH;
        const ushort* hb_c  = h_b  + (size_t)c * ZC * LB * DH;
        const ushort* hbT_c = h_bT + (size_t)c * ZC * DH * LB;
        const ushort* haT_c = h_aT + (size_t)c * ZC * DH * LA;
        ushort* Pa_c = Pa + (size_t)c * ZC * LA * DH;
        ushort* Pb_c = Pb + (size_t)c * ZC * LB * DH;
        float* rs_c = rsum + (size_t)c * ZC * LA;
        float* cs_c = csum + (size_t)c * ZC * LB;

        // scores chunk: E = exp(tanh(Ma_c @ h_b_c^T)), E^T, rowsum, colsum
        gemm_bt<1, false, false><<<dim3(LA / BM, LB / BN, ZC), blk, SHM, stream>>>(
            Ma_c, hb_c, E, ET, nullptr, nullptr, rs_c, cs_c, nullptr,
            nullptr, nullptr, nullptr, nullptr, NOSPLIT,
            LA, LB, DH, DH, DH, LB,
            (long)LA * DH, (long)LB * DH, (long)LA * LB, (long)LB * LA, LA, LA, 0);

        // fused: z<ZC -> Pa_c = (E @ h_bT_c)/rsum ; z>=ZC -> Pb_c = (ET @ h_aT_c)/csum
        gemm_bt<2, false, false><<<dim3(LA / BM, DH / BN, 2 * ZC), blk, SHM, stream>>>(
            E, hbT_c, Pa_c, nullptr, nullptr, nullptr, nullptr, nullptr, rs_c,
            ET, haT_c, Pb_c, cs_c, ZC,
            LA, DH, LB, LB, LB, DH,
            (long)LA * LB, (long)DH * LB, (long)LA * DH, 0, LA, 0, 0);
    }

    // yA = bf16(Pa @ Woa + boa + z_a), yB = bf16(Pb @ Wob + bob + z_b)
    gemm_bt<3, true, false><<<dim3(MA / BM, DA / BN, 1), blk, SHM, stream>>>(
        Pa, WoaT, yA, nullptr, boa, za16, nullptr, nullptr, nullptr,
        nullptr, nullptr, nullptr, nullptr, NOSPLIT,
        (int)MA, DA, DH, DH, DH, DA, 0, 0, 0, 0, 0, 0, 0);

    gemm_bt<3, true, false><<<dim3(MB / BM, DB / BN, 1), blk, SHM, stream>>>(
        Pb, WobT, yB, nullptr, bob, zb16, nullptr, nullptr, nullptr,
        nullptr, nullptr, nullptr, nullptr, NOSPLIT,
        (int)MB, DB, DH, DH, DH, DB, 0, 0, 0, 0, 0, 0, 0);

    // LayerNorms: bf16 y -> f32 d_out (overwrites za16/zb16 scratch, now dead)
    float* outA = (float*)d_out;
    float* outB = outA + MA * DA;
    ln_bf<768><<<dim3((unsigned)MA, 1, 1), dim3(192, 1, 1), 0, stream>>>(yA, outA, ga, beta_a);
    ln_bf<512><<<dim3((unsigned)MB, 1, 1), dim3(128, 1, 1), 0, stream>>>(yB, outB, gb, beta_b);
}